// Round 6
// baseline (26.053 us; speedup 1.0000x reference)
//
#include <hip/hip_runtime.h>

// RBF network, single fused kernel.
// inputs:  x[B=2048][F=128], centers c[H=512][F=128], sigma[1], W[O=10][H=512], b[O=10]
// Block: 8 rows x all 512 h. Thread t owns h=t (all 8 rows), acc[8].
// x delivered via wave-uniform (scalar) loads; c staged once in LDS, swizzled,
// read exactly once per element (write-once/read-once LDS floor).
// dist = |x|^2+|c|^2-2x.c ; plain store, no atomics, one graph node.

constexpr int Fdim = 128;
constexpr int Hdim = 512;
constexpr int Odim = 10;
constexpr int BM   = 8;          // rows per block
constexpr int KC   = 32;         // F chunk resident in LDS
constexpr int NCH  = Fdim / KC;  // 4
constexpr int LDR  = 516;        // rbf_s row stride

__global__ __launch_bounds__(512, 1) void rbf_all(
    const float* __restrict__ x,
    const float* __restrict__ c,
    const float* __restrict__ sigmap,
    const float* __restrict__ W,
    const float* __restrict__ bias,
    float* __restrict__ out)
{
    // c_s[h][fq-slot]: row = 32 floats (8 float4 slots), slot = fq ^ (h&7)
    __shared__ float c_s[Hdim * KC];     // 64 KB
    __shared__ float W_s[Odim][Hdim];    // 20.5 KB
    __shared__ float rbf_s[BM][LDR];     // 16.5 KB
    __shared__ float xn_s[BM];
    __shared__ float cn_s[Hdim];         // ~103 KB total -> 1 block/CU

    const int tid  = threadIdx.x;
    const int lane = tid & 63;
    const int wave = tid >> 6;          // 0..7
    const int row0 = blockIdx.x * BM;

    const float4* x4 = reinterpret_cast<const float4*>(x);
    const float4* c4 = reinterpret_cast<const float4*>(c);

    // ---- stage W (once)
#pragma unroll
    for (int k = 0; k < (Odim * Hdim) / 512; ++k) {   // 10
        int idx = tid + 512 * k;
        W_s[idx >> 9][idx & 511] = W[idx];
    }

    // ---- x row norms (once): 256 threads, one float4 each
    if (tid < 256) {
        int r  = tid >> 5;    // 0..7
        int fq = tid & 31;
        float4 v = x4[(size_t)(row0 + r) * (Fdim / 4) + fq];
        float s = v.x * v.x + v.y * v.y + v.z * v.z + v.w * v.w;
#pragma unroll
        for (int sft = 1; sft < 32; sft <<= 1) s += __shfl_xor(s, sft, 64);
        if (fq == 0) xn_s[r] = s;
    }

    // ---- c staging state: thread covers h = sh+64p, f-quad sfq (within chunk)
    const int sfq = tid & 7;    // f-quad within chunk
    const int sh  = tid >> 3;   // 0..63

    float4 pre[8];
    float cn_part[8];
#pragma unroll
    for (int p = 0; p < 8; ++p) cn_part[p] = 0.0f;

    // prologue: chunk 0 -> regs -> LDS (swizzled b128 write)
#pragma unroll
    for (int p = 0; p < 8; ++p)
        pre[p] = c4[(size_t)(sh + 64 * p) * (Fdim / 4) + sfq];
#pragma unroll
    for (int p = 0; p < 8; ++p) {
        float4 v = pre[p];
        int h = sh + 64 * p;
        *reinterpret_cast<float4*>(&c_s[h * KC + ((sfq ^ (h & 7)) << 2)]) = v;
        cn_part[p] += v.x * v.x + v.y * v.y + v.z * v.z + v.w * v.w;
    }
    __syncthreads();   // c_s chunk0 + W_s + xn_s visible

    // ---- main loop: thread owns h = tid, rows 0..7; x via uniform (scalar) loads
    float acc[8];
#pragma unroll
    for (int r = 0; r < 8; ++r) acc[r] = 0.0f;

    const int hown = tid;
    const int hswz = hown & 7;

    // x quad pointers: x4[(row0+r)*32 + k*8 + fg]  (wave-uniform indices)
    float4 xc[8];
#pragma unroll
    for (int r = 0; r < 8; ++r)
        xc[r] = x4[(size_t)(row0 + r) * (Fdim / 4) + 0];   // chunk0, fg0

    for (int k = 0; k < NCH; ++k) {
        // issue next chunk's c loads (latency hides under compute)
        if (k + 1 < NCH) {
#pragma unroll
            for (int p = 0; p < 8; ++p)
                pre[p] = c4[(size_t)(sh + 64 * p) * (Fdim / 4) + (k + 1) * (KC / 4) + sfq];
        }

#pragma unroll
        for (int fg = 0; fg < KC / 4; ++fg) {   // 8 f-quad groups
            // prefetch next x group (uniform loads, scalar pipe)
            float4 xnx[8];
            {
                int nk = k, nfg = fg + 1;
                if (nfg == KC / 4) { nfg = 0; nk = k + 1; }
                if (nk < NCH) {
#pragma unroll
                    for (int r = 0; r < 8; ++r)
                        xnx[r] = x4[(size_t)(row0 + r) * (Fdim / 4) + nk * (KC / 4) + nfg];
                } else {
#pragma unroll
                    for (int r = 0; r < 8; ++r) xnx[r] = xc[r];
                }
            }

            float4 cv = *reinterpret_cast<const float4*>(
                &c_s[hown * KC + ((fg ^ hswz) << 2)]);

#pragma unroll
            for (int r = 0; r < 8; ++r) {
                acc[r] = fmaf(xc[r].x, cv.x, acc[r]);
                acc[r] = fmaf(xc[r].y, cv.y, acc[r]);
                acc[r] = fmaf(xc[r].z, cv.z, acc[r]);
                acc[r] = fmaf(xc[r].w, cv.w, acc[r]);
            }
#pragma unroll
            for (int r = 0; r < 8; ++r) xc[r] = xnx[r];
        }

        if (k + 1 < NCH) {
            __syncthreads();   // all done reading c_s chunk k
#pragma unroll
            for (int p = 0; p < 8; ++p) {
                float4 v = pre[p];
                int h = sh + 64 * p;
                *reinterpret_cast<float4*>(&c_s[h * KC + ((sfq ^ (h & 7)) << 2)]) = v;
                cn_part[p] += v.x * v.x + v.y * v.y + v.z * v.z + v.w * v.w;
            }
            __syncthreads();   // chunk k+1 visible
        }
    }

    // ---- publish center norms (reduce over the 8 sfq-lanes per h)
#pragma unroll
    for (int p = 0; p < 8; ++p) {
        float s = cn_part[p];
        s += __shfl_xor(s, 1, 64);
        s += __shfl_xor(s, 2, 64);
        s += __shfl_xor(s, 4, 64);
        cn_part[p] = s;
    }
    if (sfq == 0) {
#pragma unroll
        for (int p = 0; p < 8; ++p) cn_s[sh + 64 * p] = cn_part[p];
    }
    __syncthreads();

    // ---- rbf = exp(dist*scale): thread t -> column h=t of rbf_s
    const float sg    = sigmap[0];
    const float scale = -1.0f / (2.0f * sg * sg);
    {
        float cn = cn_s[hown];
#pragma unroll
        for (int r = 0; r < 8; ++r) {
            float d = xn_s[r] + cn - 2.0f * acc[r];
            rbf_s[r][hown] = __expf(d * scale);
        }
    }
    __syncthreads();

    // ---- GEMV epilogue: wave = row, lane h-mapping contiguous (conflict-free)
    {
        const int row = wave;   // 0..7
        float po[Odim];
#pragma unroll
        for (int o = 0; o < Odim; ++o) po[o] = 0.0f;

#pragma unroll
        for (int k = 0; k < 8; ++k) {
            int h = lane + 64 * k;
            float r = rbf_s[row][h];
#pragma unroll
            for (int o = 0; o < Odim; ++o)
                po[o] = fmaf(r, W_s[o][h], po[o]);
        }
#pragma unroll
        for (int s = 1; s < 64; s <<= 1) {
#pragma unroll
            for (int o = 0; o < Odim; ++o)
                po[o] += __shfl_xor(po[o], s, 64);
        }
        if (lane == 0) {
#pragma unroll
            for (int o = 0; o < Odim; ++o)
                out[(size_t)(row0 + row) * Odim + o] = po[o] + bias[o];
        }
    }
}

extern "C" void kernel_launch(void* const* d_in, const int* in_sizes, int n_in,
                              void* d_out, int out_size, void* d_ws, size_t ws_size,
                              hipStream_t stream) {
    const float* x  = (const float*)d_in[0];
    const float* c  = (const float*)d_in[1];
    const float* sg = (const float*)d_in[2];
    const float* W  = (const float*)d_in[3];
    const float* b  = (const float*)d_in[4];
    float* out      = (float*)d_out;

    const int B = in_sizes[0] / Fdim;   // 2048

    rbf_all<<<B / BM, 512, 0, stream>>>(x, c, sg, W, b, out);
}

// Round 7
// 20.498 us; speedup vs baseline: 1.2710x; 1.2710x over previous
//
#include <hip/hip_runtime.h>

// RBF network, single fused kernel (one graph node).
// inputs:  x[B=2048][F=128], centers c[H=512][F=128], sigma[1], W[O=10][H=512], b[O=10]
// Block: 8 rows x all 512 h; 512 thr. Main loop = R4 mapping (wave: 4 rows x 128-h slice,
// lane: 4r x 2h), x via LDS broadcast b128, c via contiguous b64.
// New vs R4: c dbuf (KC=16 x2), transpose-staged b128 LDS writes, W-in-registers epilogue
// with 3-step butterfly + 80-thread finish. dist = |x|^2+|c|^2-2x.c.

constexpr int Fdim = 128;
constexpr int Hdim = 512;
constexpr int Odim = 10;
constexpr int BM   = 8;          // rows per block
constexpr int KC   = 16;         // F chunk per buffer
constexpr int NCH  = Fdim / KC;  // 8
constexpr int LDXT = 12;         // xT row stride (48B, 16B-aligned quads)

__global__ __launch_bounds__(512, 1) void rbf_all(
    const float* __restrict__ x,
    const float* __restrict__ c,
    const float* __restrict__ sigmap,
    const float* __restrict__ W,
    const float* __restrict__ bias,
    float* __restrict__ out)
{
    __shared__ float c_s[2][KC][Hdim];    // 64 KB   f-major, double-buffered
    __shared__ float xT[Fdim][LDXT];      //  6 KB   x transposed (once)
    __shared__ float rbf_s[BM][Hdim];     // 16 KB
    __shared__ float cn_tmp[4][Hdim];     //  8 KB   per-fq center-norm partials
    __shared__ float po_s[BM][8][Odim];   //  2.5 KB epilogue group partials
    __shared__ float xn_s[BM];            //         total ~97 KB

    const int tid  = threadIdx.x;
    const int lane = tid & 63;
    const int wave = tid >> 6;           // 0..7
    const int wr   = wave >> 2;          // rows 4wr..4wr+3
    const int wh   = wave & 3;           // h in [wh*128, wh*128+128)
    const int row0 = blockIdx.x * BM;

    const float4* x4 = reinterpret_cast<const float4*>(x);
    const float4* c4 = reinterpret_cast<const float4*>(c);

    // ---- stage x transposed (once) + row norms
    if (tid < 256) {
        int r  = tid >> 5;    // 0..7
        int fq = tid & 31;
        float4 v = x4[(size_t)(row0 + r) * (Fdim / 4) + fq];
        xT[4 * fq + 0][r] = v.x;
        xT[4 * fq + 1][r] = v.y;
        xT[4 * fq + 2][r] = v.z;
        xT[4 * fq + 3][r] = v.w;
        float s = v.x * v.x + v.y * v.y + v.z * v.z + v.w * v.w;
#pragma unroll
        for (int sft = 1; sft < 32; sft <<= 1) s += __shfl_xor(s, sft, 64);
        if (fq == 0) xn_s[r] = s;
    }

    // ---- c staging: thread owns 4h x 4f tile; transpose in regs, b128 writes
    const int fq = tid >> 7;    // 0..3  f-quad within chunk
    const int hq = tid & 127;   // 0..127 h-quad

    float4 pre[4];
    float cnp[4] = {0.0f, 0.0f, 0.0f, 0.0f};

#define CLOAD(k)                                                              \
    {                                                                         \
        _Pragma("unroll")                                                     \
        for (int i = 0; i < 4; ++i)                                           \
            pre[i] = c4[(size_t)(4 * hq + i) * (Fdim / 4) + (k) * 4 + fq];    \
    }

#define CWRITE(k)                                                             \
    {                                                                         \
        float a0[4] = {pre[0].x, pre[0].y, pre[0].z, pre[0].w};               \
        float a1[4] = {pre[1].x, pre[1].y, pre[1].z, pre[1].w};               \
        float a2[4] = {pre[2].x, pre[2].y, pre[2].z, pre[2].w};               \
        float a3[4] = {pre[3].x, pre[3].y, pre[3].z, pre[3].w};               \
        _Pragma("unroll")                                                     \
        for (int j = 0; j < 4; ++j) {                                         \
            float4 w4;                                                        \
            w4.x = a0[j]; w4.y = a1[j]; w4.z = a2[j]; w4.w = a3[j];           \
            *reinterpret_cast<float4*>(&c_s[(k) & 1][4 * fq + j][4 * hq]) = w4; \
        }                                                                     \
        cnp[0] += pre[0].x * pre[0].x + pre[0].y * pre[0].y +                 \
                  pre[0].z * pre[0].z + pre[0].w * pre[0].w;                  \
        cnp[1] += pre[1].x * pre[1].x + pre[1].y * pre[1].y +                 \
                  pre[1].z * pre[1].z + pre[1].w * pre[1].w;                  \
        cnp[2] += pre[2].x * pre[2].x + pre[2].y * pre[2].y +                 \
                  pre[2].z * pre[2].z + pre[2].w * pre[2].w;                  \
        cnp[3] += pre[3].x * pre[3].x + pre[3].y * pre[3].y +                 \
                  pre[3].z * pre[3].z + pre[3].w * pre[3].w;                  \
    }

    CLOAD(0); CWRITE(0); CLOAD(1);
    __syncthreads();   // buf0 + xT + xn visible

    float acc[4][2];
#pragma unroll
    for (int i = 0; i < 4; ++i) { acc[i][0] = 0.0f; acc[i][1] = 0.0f; }

    for (int k = 0; k < NCH; ++k) {
        if (k + 1 < NCH) CWRITE(k + 1);   // to buf[(k+1)&1] (other buffer)
        if (k + 2 < NCH) CLOAD(k + 2);    // issue next globals (latency hidden)

#pragma unroll
        for (int f = 0; f < KC; ++f) {
            float4 xv = *reinterpret_cast<const float4*>(&xT[k * KC + f][4 * wr]);
            float2 cv = *reinterpret_cast<const float2*>(
                &c_s[k & 1][f][wh * 128 + 2 * lane]);
            acc[0][0] = fmaf(xv.x, cv.x, acc[0][0]);
            acc[0][1] = fmaf(xv.x, cv.y, acc[0][1]);
            acc[1][0] = fmaf(xv.y, cv.x, acc[1][0]);
            acc[1][1] = fmaf(xv.y, cv.y, acc[1][1]);
            acc[2][0] = fmaf(xv.z, cv.x, acc[2][0]);
            acc[2][1] = fmaf(xv.z, cv.y, acc[2][1]);
            acc[3][0] = fmaf(xv.w, cv.x, acc[3][0]);
            acc[3][1] = fmaf(xv.w, cv.y, acc[3][1]);
        }
        __syncthreads();   // writes of chunk k+1 visible; buf[k&1] free for k+2
    }
#undef CLOAD
#undef CWRITE

    // ---- W into registers (issued here; latency hides under norm publish + exp)
    float2 W2[Odim][4];
#pragma unroll
    for (int o = 0; o < Odim; ++o)
#pragma unroll
        for (int k = 0; k < 4; ++k)
            W2[o][k] = *reinterpret_cast<const float2*>(
                &W[o * Hdim + 2 * lane + 128 * k]);

    // ---- publish center-norm partials, then read-reduce per lane
#pragma unroll
    for (int i = 0; i < 4; ++i) cn_tmp[fq][4 * hq + i] = cnp[i];
    __syncthreads();

    const float sg    = sigmap[0];
    const float scale = -1.0f / (2.0f * sg * sg);
    {
        float2 cn;
        cn.x = 0.0f; cn.y = 0.0f;
#pragma unroll
        for (int q = 0; q < 4; ++q) {
            float2 t = *reinterpret_cast<const float2*>(
                &cn_tmp[q][wh * 128 + 2 * lane]);
            cn.x += t.x; cn.y += t.y;
        }
#pragma unroll
        for (int i = 0; i < 4; ++i) {
            float xn = xn_s[4 * wr + i];
            float2 rv;
            rv.x = __expf((xn + cn.x - 2.0f * acc[i][0]) * scale);
            rv.y = __expf((xn + cn.y - 2.0f * acc[i][1]) * scale);
            *reinterpret_cast<float2*>(&rbf_s[4 * wr + i][wh * 128 + 2 * lane]) = rv;
        }
    }
    __syncthreads();

    // ---- epilogue: wave = row; lane covers h = 2*lane + 128k; W from regs
    {
        const int row = wave;
        float po[Odim];
#pragma unroll
        for (int o = 0; o < Odim; ++o) po[o] = 0.0f;

#pragma unroll
        for (int k = 0; k < 4; ++k) {
            float2 rv = *reinterpret_cast<const float2*>(
                &rbf_s[row][2 * lane + 128 * k]);
#pragma unroll
            for (int o = 0; o < Odim; ++o) {
                po[o] = fmaf(rv.x, W2[o][k].x, po[o]);
                po[o] = fmaf(rv.y, W2[o][k].y, po[o]);
            }
        }
        // 3-step butterfly -> 8-lane-group sums, then group partials to LDS
#pragma unroll
        for (int s = 1; s < 8; s <<= 1) {
#pragma unroll
            for (int o = 0; o < Odim; ++o)
                po[o] += __shfl_xor(po[o], s, 64);
        }
        if ((lane & 7) == 0) {
#pragma unroll
            for (int o = 0; o < Odim; ++o)
                po_s[row][lane >> 3][o] = po[o];
        }
    }
    __syncthreads();

    // ---- finish: 80 threads, one (row,o) each
    if (tid < BM * Odim) {
        int w = tid / Odim;
        int o = tid - w * Odim;
        float v = bias[o];
#pragma unroll
        for (int g = 0; g < 8; ++g) v += po_s[w][g][o];
        out[(size_t)(row0 + w) * Odim + o] = v;
    }
}

extern "C" void kernel_launch(void* const* d_in, const int* in_sizes, int n_in,
                              void* d_out, int out_size, void* d_ws, size_t ws_size,
                              hipStream_t stream) {
    const float* x  = (const float*)d_in[0];
    const float* c  = (const float*)d_in[1];
    const float* sg = (const float*)d_in[2];
    const float* W  = (const float*)d_in[3];
    const float* b  = (const float*)d_in[4];
    float* out      = (float*)d_out;

    const int B = in_sizes[0] / Fdim;   // 2048

    rbf_all<<<B / BM, 512, 0, stream>>>(x, c, sg, W, b, out);
}

// Round 8
// 19.155 us; speedup vs baseline: 1.3601x; 1.0701x over previous
//
#include <hip/hip_runtime.h>

// RBF network, single fused kernel (one graph node).
// inputs:  x[B=2048][F=128], centers c[H=512][F=128], sigma[1], W[O=10][H=512], b[O=10]
// Block: 8 rows x all 512 h; 512 thr. Main loop = R4 mapping (wave: 4 rows x 128-h slice,
// lane tile 4r x 2h), x via LDS-broadcast b128, c via contiguous b64.
// c double-buffered KC=16, schedule: compute(k) -> write(k+1) -> load(k+2) -> barrier
// (write-late: global latency hides under compute). W-in-registers epilogue,
// 3-step butterfly + 80-thread finish. dist = |x|^2+|c|^2-2x.c.

constexpr int Fdim = 128;
constexpr int Hdim = 512;
constexpr int Odim = 10;
constexpr int BM   = 8;          // rows per block
constexpr int KC   = 16;         // F chunk per buffer
constexpr int NCH  = Fdim / KC;  // 8
constexpr int LDXT = 12;         // xT row stride (48B, 16B-aligned quads)

__global__ __launch_bounds__(512, 1) void rbf_all(
    const float* __restrict__ x,
    const float* __restrict__ c,
    const float* __restrict__ sigmap,
    const float* __restrict__ W,
    const float* __restrict__ bias,
    float* __restrict__ out)
{
    __shared__ float c_s[2][KC][Hdim];    // 64 KB  f-major, double-buffered
    __shared__ float xT[Fdim][LDXT];      //  6 KB  x transposed (once)
    __shared__ float rbf_s[BM][Hdim];     // 16 KB
    __shared__ float cn_s[Hdim];          //  2 KB
    __shared__ float po_s[BM][8][Odim];   //  2.5 KB
    __shared__ float xn_s[BM];            // total ~91 KB

    const int tid  = threadIdx.x;
    const int lane = tid & 63;
    const int wave = tid >> 6;           // 0..7
    const int wr   = wave >> 2;          // rows 4wr..4wr+3
    const int wh   = wave & 3;           // h in [wh*128, wh*128+128)
    const int row0 = blockIdx.x * BM;

    const float4* x4 = reinterpret_cast<const float4*>(x);
    const float4* c4 = reinterpret_cast<const float4*>(c);

    // ---- c staging state: thread owns f-quad sfq (of 4 per chunk), h = sh + 128p
    const int sfq = tid & 3;
    const int sh  = tid >> 2;    // 0..127

    float4 pre[4];
    float cnp[4] = {0.0f, 0.0f, 0.0f, 0.0f};

#define CLOAD(k)                                                              \
    {                                                                         \
        _Pragma("unroll")                                                     \
        for (int p = 0; p < 4; ++p)                                           \
            pre[p] = c4[(size_t)(sh + 128 * p) * (Fdim / 4) + (k) * 4 + sfq]; \
    }
#define CWRITE(k)                                                             \
    {                                                                         \
        _Pragma("unroll")                                                     \
        for (int p = 0; p < 4; ++p) {                                         \
            float4 v = pre[p];                                                \
            int h = sh + 128 * p;                                             \
            c_s[(k) & 1][4 * sfq + 0][h] = v.x;                               \
            c_s[(k) & 1][4 * sfq + 1][h] = v.y;                               \
            c_s[(k) & 1][4 * sfq + 2][h] = v.z;                               \
            c_s[(k) & 1][4 * sfq + 3][h] = v.w;                               \
            cnp[p] += v.x * v.x + v.y * v.y + v.z * v.z + v.w * v.w;          \
        }                                                                     \
    }

    CLOAD(0);   // issue earliest

    // ---- stage x transposed (once) + row norms (hides chunk0 load latency)
    if (tid < 256) {
        int r  = tid >> 5;    // 0..7
        int fq = tid & 31;
        float4 v = x4[(size_t)(row0 + r) * (Fdim / 4) + fq];
        xT[4 * fq + 0][r] = v.x;
        xT[4 * fq + 1][r] = v.y;
        xT[4 * fq + 2][r] = v.z;
        xT[4 * fq + 3][r] = v.w;
        float s = v.x * v.x + v.y * v.y + v.z * v.z + v.w * v.w;
#pragma unroll
        for (int sft = 1; sft < 32; sft <<= 1) s += __shfl_xor(s, sft, 64);
        if (fq == 0) xn_s[r] = s;
    }

    CWRITE(0);
    CLOAD(1);
    __syncthreads();   // buf0 + xT + xn visible

    float acc[4][2];
#pragma unroll
    for (int i = 0; i < 4; ++i) { acc[i][0] = 0.0f; acc[i][1] = 0.0f; }

    for (int k = 0; k < NCH; ++k) {
        // ---- compute chunk k from buf[k&1] (hides CLOAD(k+1) latency)
#pragma unroll
        for (int f = 0; f < KC; ++f) {
            float4 xv = *reinterpret_cast<const float4*>(&xT[k * KC + f][4 * wr]);
            float2 cv = *reinterpret_cast<const float2*>(
                &c_s[k & 1][f][wh * 128 + 2 * lane]);
            acc[0][0] = fmaf(xv.x, cv.x, acc[0][0]);
            acc[0][1] = fmaf(xv.x, cv.y, acc[0][1]);
            acc[1][0] = fmaf(xv.y, cv.x, acc[1][0]);
            acc[1][1] = fmaf(xv.y, cv.y, acc[1][1]);
            acc[2][0] = fmaf(xv.z, cv.x, acc[2][0]);
            acc[2][1] = fmaf(xv.z, cv.y, acc[2][1]);
            acc[3][0] = fmaf(xv.w, cv.x, acc[3][0]);
            acc[3][1] = fmaf(xv.w, cv.y, acc[3][1]);
        }
        if (k + 1 < NCH) {
            CWRITE(k + 1);           // other buffer: no race with readers of buf[k&1]
            if (k + 2 < NCH) CLOAD(k + 2);   // refill pre; hides under compute(k+1)
            __syncthreads();         // writes visible; all done reading buf[k&1]
        }
    }
#undef CLOAD
#undef CWRITE

    // ---- W into registers (L2 latency hides under cn/exp phase below)
    float2 W2[Odim][4];
#pragma unroll
    for (int o = 0; o < Odim; ++o)
#pragma unroll
        for (int kk = 0; kk < 4; ++kk)
            W2[o][kk] = *reinterpret_cast<const float2*>(
                &W[o * Hdim + 2 * lane + 128 * kk]);

    // ---- center norms: reduce over the 4 sfq-lanes, publish
#pragma unroll
    for (int p = 0; p < 4; ++p) {
        float s = cnp[p];
        s += __shfl_xor(s, 1, 64);
        s += __shfl_xor(s, 2, 64);
        cnp[p] = s;
    }
    if (sfq == 0) {
#pragma unroll
        for (int p = 0; p < 4; ++p) cn_s[sh + 128 * p] = cnp[p];
    }
    __syncthreads();

    // ---- rbf = exp(dist*scale) -> rbf_s
    const float sg    = sigmap[0];
    const float scale = -1.0f / (2.0f * sg * sg);
    {
        float2 cn = *reinterpret_cast<const float2*>(&cn_s[wh * 128 + 2 * lane]);
#pragma unroll
        for (int i = 0; i < 4; ++i) {
            float xn = xn_s[4 * wr + i];
            float2 rv;
            rv.x = __expf((xn + cn.x - 2.0f * acc[i][0]) * scale);
            rv.y = __expf((xn + cn.y - 2.0f * acc[i][1]) * scale);
            *reinterpret_cast<float2*>(&rbf_s[4 * wr + i][wh * 128 + 2 * lane]) = rv;
        }
    }
    __syncthreads();

    // ---- epilogue: wave = row; lane covers h = 2*lane + 128k; W from regs
    {
        const int row = wave;
        float po[Odim];
#pragma unroll
        for (int o = 0; o < Odim; ++o) po[o] = 0.0f;

#pragma unroll
        for (int kk = 0; kk < 4; ++kk) {
            float2 rv = *reinterpret_cast<const float2*>(
                &rbf_s[row][2 * lane + 128 * kk]);
#pragma unroll
            for (int o = 0; o < Odim; ++o) {
                po[o] = fmaf(rv.x, W2[o][kk].x, po[o]);
                po[o] = fmaf(rv.y, W2[o][kk].y, po[o]);
            }
        }
#pragma unroll
        for (int s = 1; s < 8; s <<= 1) {
#pragma unroll
            for (int o = 0; o < Odim; ++o)
                po[o] += __shfl_xor(po[o], s, 64);
        }
        if ((lane & 7) == 0) {
#pragma unroll
            for (int o = 0; o < Odim; ++o)
                po_s[row][lane >> 3][o] = po[o];
        }
    }
    __syncthreads();

    // ---- finish: 80 threads, one (row,o) each
    if (tid < BM * Odim) {
        int w = tid / Odim;
        int o = tid - w * Odim;
        float v = bias[o];
#pragma unroll
        for (int g = 0; g < 8; ++g) v += po_s[w][g][o];
        out[(size_t)(row0 + w) * Odim + o] = v;
    }
}

extern "C" void kernel_launch(void* const* d_in, const int* in_sizes, int n_in,
                              void* d_out, int out_size, void* d_ws, size_t ws_size,
                              hipStream_t stream) {
    const float* x  = (const float*)d_in[0];
    const float* c  = (const float*)d_in[1];
    const float* sg = (const float*)d_in[2];
    const float* W  = (const float*)d_in[3];
    const float* b  = (const float*)d_in[4];
    float* out      = (float*)d_out;

    const int B = in_sizes[0] / Fdim;   // 2048

    rbf_all<<<B / BM, 512, 0, stream>>>(x, c, sg, W, b, out);
}

// Round 9
// 17.884 us; speedup vs baseline: 1.4568x; 1.0711x over previous
//
#include <hip/hip_runtime.h>

// RBF network, single fused kernel (one graph node).
// R4 base (measured 17.64us) with ONLY the epilogue replaced:
//   - W in registers (L1-resident) instead of W_s LDS tile
//   - 3-step butterfly + 80-thread finish instead of 6-step + lane0 store
// Main loop / staging / norms byte-identical to R4.
// inputs:  x[B=2048][F=128], centers c[H=512][F=128], sigma[1], W[O=10][H=512], b[O=10]

constexpr int Fdim = 128;
constexpr int Hdim = 512;
constexpr int Odim = 10;
constexpr int BM   = 8;          // rows per block
constexpr int KC   = 32;         // F chunk resident in LDS
constexpr int NCH  = Fdim / KC;  // 4
constexpr int LDC  = 513;        // cT row stride (2-way-free writes, conflict-free b64 reads)
constexpr int LDXT = 12;         // xT row stride
constexpr int LDR  = 516;        // rbf_s row stride

__global__ __launch_bounds__(512, 1) void rbf_all(
    const float* __restrict__ x,
    const float* __restrict__ c,
    const float* __restrict__ sigmap,
    const float* __restrict__ W,
    const float* __restrict__ bias,
    float* __restrict__ out)
{
    __shared__ float cT[KC][LDC];        // 65.7 KB  current c chunk, f-major
    __shared__ float xT[Fdim][LDXT];     //  6.1 KB  all x rows, f-major (staged once)
    __shared__ float rbf_s[BM][LDR];     // 16.5 KB
    __shared__ float po_s[BM][8][Odim];  //  2.5 KB  epilogue group partials
    __shared__ float xn_s[BM];
    __shared__ float cn_s[Hdim];         // total ~93 KB -> 1 block/CU (grid=256)

    const int tid  = threadIdx.x;
    const int lane = tid & 63;
    const int wave = tid >> 6;          // 0..7
    const int wr   = wave >> 2;         // rows 4wr..4wr+3
    const int wh   = wave & 3;          // h in [wh*128, wh*128+128)
    const int row0 = blockIdx.x * BM;

    const float4* x4 = reinterpret_cast<const float4*>(x);
    const float4* c4 = reinterpret_cast<const float4*>(c);

    // ---- stage ALL x, transposed (once), + row norms
    if (tid < 256) {
        int r  = tid >> 5;    // 0..7
        int fq = tid & 31;    // float4 index along f
        float4 v = x4[(size_t)(row0 + r) * (Fdim / 4) + fq];
        xT[4 * fq + 0][r] = v.x;
        xT[4 * fq + 1][r] = v.y;
        xT[4 * fq + 2][r] = v.z;
        xT[4 * fq + 3][r] = v.w;
        float s = v.x * v.x + v.y * v.y + v.z * v.z + v.w * v.w;
#pragma unroll
        for (int sft = 1; sft < 32; sft <<= 1) s += __shfl_xor(s, sft, 64);
        if (fq == 0) xn_s[r] = s;
    }

    // ---- c staging: reg-prefetch double buffer (R4 schedule)
    const int f4 = tid & 7;     // f-quad within chunk
    const int hh = tid >> 3;    // 0..63

    float4 pre[8];
    float cn_part[8];
#pragma unroll
    for (int p = 0; p < 8; ++p) cn_part[p] = 0.0f;

    // prologue: load chunk 0 into regs, write to LDS
#pragma unroll
    for (int p = 0; p < 8; ++p)
        pre[p] = c4[(size_t)(hh + 64 * p) * (Fdim / 4) + f4];
#pragma unroll
    for (int p = 0; p < 8; ++p) {
        float4 v = pre[p];
        int h = hh + 64 * p;
        cT[4 * f4 + 0][h] = v.x;
        cT[4 * f4 + 1][h] = v.y;
        cT[4 * f4 + 2][h] = v.z;
        cT[4 * f4 + 3][h] = v.w;
        cn_part[p] += v.x * v.x + v.y * v.y + v.z * v.z + v.w * v.w;
    }
    __syncthreads();   // cT chunk0 + xT + xn visible

    float acc[4][2];
#pragma unroll
    for (int i = 0; i < 4; ++i) { acc[i][0] = 0.0f; acc[i][1] = 0.0f; }

    for (int k = 0; k < NCH; ++k) {
        // issue next chunk's global loads (latency hides under compute below)
        if (k + 1 < NCH) {
#pragma unroll
            for (int p = 0; p < 8; ++p)
                pre[p] = c4[(size_t)(hh + 64 * p) * (Fdim / 4) + (k + 1) * (KC / 4) + f4];
        }

        // ---- compute chunk k: x read wave-uniform b128 (broadcast), c read b64 contiguous
#pragma unroll 8
        for (int f = 0; f < KC; ++f) {
            float4 xv = *reinterpret_cast<const float4*>(&xT[k * KC + f][4 * wr]);
            float2 cv = *reinterpret_cast<const float2*>(&cT[f][wh * 128 + 2 * lane]);
            acc[0][0] = fmaf(xv.x, cv.x, acc[0][0]);
            acc[0][1] = fmaf(xv.x, cv.y, acc[0][1]);
            acc[1][0] = fmaf(xv.y, cv.x, acc[1][0]);
            acc[1][1] = fmaf(xv.y, cv.y, acc[1][1]);
            acc[2][0] = fmaf(xv.z, cv.x, acc[2][0]);
            acc[2][1] = fmaf(xv.z, cv.y, acc[2][1]);
            acc[3][0] = fmaf(xv.w, cv.x, acc[3][0]);
            acc[3][1] = fmaf(xv.w, cv.y, acc[3][1]);
        }

        if (k + 1 < NCH) {
            __syncthreads();   // everyone done reading cT chunk k
#pragma unroll
            for (int p = 0; p < 8; ++p) {
                float4 v = pre[p];
                int h = hh + 64 * p;
                cT[4 * f4 + 0][h] = v.x;
                cT[4 * f4 + 1][h] = v.y;
                cT[4 * f4 + 2][h] = v.z;
                cT[4 * f4 + 3][h] = v.w;
                cn_part[p] += v.x * v.x + v.y * v.y + v.z * v.z + v.w * v.w;
            }
            __syncthreads();   // chunk k+1 visible
        }
    }

    // ---- W into registers (L1-resident; latency hides under cn/exp phase)
    float2 W2[Odim][4];
#pragma unroll
    for (int o = 0; o < Odim; ++o)
#pragma unroll
        for (int kk = 0; kk < 4; ++kk)
            W2[o][kk] = *reinterpret_cast<const float2*>(
                &W[o * Hdim + 2 * lane + 128 * kk]);

    // ---- publish center norms (reduce over the 8 f4-lanes)
#pragma unroll
    for (int p = 0; p < 8; ++p) {
        float s = cn_part[p];
        s += __shfl_xor(s, 1, 64);
        s += __shfl_xor(s, 2, 64);
        s += __shfl_xor(s, 4, 64);
        cn_part[p] = s;
    }
    if (f4 == 0) {
#pragma unroll
        for (int p = 0; p < 8; ++p) cn_s[hh + 64 * p] = cn_part[p];
    }
    __syncthreads();

    // ---- rbf = exp(dist*scale) -> rbf_s
    const float sg    = sigmap[0];
    const float scale = -1.0f / (2.0f * sg * sg);
    {
        float2 cn = *reinterpret_cast<const float2*>(&cn_s[wh * 128 + 2 * lane]);
#pragma unroll
        for (int i = 0; i < 4; ++i) {
            float xn = xn_s[4 * wr + i];
            float2 rv;
            rv.x = __expf((xn + cn.x - 2.0f * acc[i][0]) * scale);
            rv.y = __expf((xn + cn.y - 2.0f * acc[i][1]) * scale);
            *reinterpret_cast<float2*>(&rbf_s[4 * wr + i][wh * 128 + 2 * lane]) = rv;
        }
    }
    __syncthreads();

    // ---- epilogue: wave = row; lane covers h = 2*lane + 128k; W from regs
    {
        const int row = wave;   // 0..7
        float po[Odim];
#pragma unroll
        for (int o = 0; o < Odim; ++o) po[o] = 0.0f;

#pragma unroll
        for (int kk = 0; kk < 4; ++kk) {
            float2 rv = *reinterpret_cast<const float2*>(
                &rbf_s[row][2 * lane + 128 * kk]);
#pragma unroll
            for (int o = 0; o < Odim; ++o) {
                po[o] = fmaf(rv.x, W2[o][kk].x, po[o]);
                po[o] = fmaf(rv.y, W2[o][kk].y, po[o]);
            }
        }
        // 3-step butterfly -> 8-lane-group sums -> LDS
#pragma unroll
        for (int s = 1; s < 8; s <<= 1) {
#pragma unroll
            for (int o = 0; o < Odim; ++o)
                po[o] += __shfl_xor(po[o], s, 64);
        }
        if ((lane & 7) == 0) {
#pragma unroll
            for (int o = 0; o < Odim; ++o)
                po_s[row][lane >> 3][o] = po[o];
        }
    }
    __syncthreads();

    // ---- finish: 80 threads, one (row,o) each
    if (tid < BM * Odim) {
        int w = tid / Odim;
        int o = tid - w * Odim;
        float v = bias[o];
#pragma unroll
        for (int g = 0; g < 8; ++g) v += po_s[w][g][o];
        out[(size_t)(row0 + w) * Odim + o] = v;
    }
}

extern "C" void kernel_launch(void* const* d_in, const int* in_sizes, int n_in,
                              void* d_out, int out_size, void* d_ws, size_t ws_size,
                              hipStream_t stream) {
    const float* x  = (const float*)d_in[0];
    const float* c  = (const float*)d_in[1];
    const float* sg = (const float*)d_in[2];
    const float* W  = (const float*)d_in[3];
    const float* b  = (const float*)d_in[4];
    float* out      = (float*)d_out;

    const int B = in_sizes[0] / Fdim;   // 2048

    rbf_all<<<B / BM, 512, 0, stream>>>(x, c, sg, W, b, out);
}